// Round 2
// baseline (154.516 us; speedup 1.0000x reference)
//
#include <hip/hip_runtime.h>

// Fused attention block: qkv = x@Wqkv+b; per-head softmax(QK^T/8)V; y = att@Wproj+b
// B=16 T=512 H=768 NH=12 HS=64. All GEMM/attn compute in bf16 MFMA (16x16x32), fp32 accum.

typedef unsigned short u16;
typedef __bf16 bf16x8 __attribute__((ext_vector_type(8)));
typedef float f32x4 __attribute__((ext_vector_type(4)));
typedef unsigned short u16x8 __attribute__((ext_vector_type(8)));

__device__ __forceinline__ u16 f2b(float f) {
  union { float f; unsigned int u; } v; v.f = f;
  unsigned int u = v.u;
  return (u16)((u + 0x7FFFu + ((u >> 16) & 1u)) >> 16);  // RNE
}

__device__ __forceinline__ void gload_lds16(const u16* gsrc, u16* ldst) {
  __builtin_amdgcn_global_load_lds(
      (const __attribute__((address_space(1))) void*)gsrc,
      (__attribute__((address_space(3))) void*)ldst,
      16, 0, 0);
}

__device__ __forceinline__ bf16x8 lds_read16(const u16* p) {
  return __builtin_bit_cast(bf16x8, *(const int4*)p);
}

// ---------------- converts ----------------

__global__ __launch_bounds__(256) void cvt_x(const float* __restrict__ in,
                                             u16* __restrict__ out, int n8) {
  int i = blockIdx.x * 256 + threadIdx.x;
  if (i >= n8) return;
  float4 v0 = ((const float4*)in)[(size_t)i * 2];
  float4 v1 = ((const float4*)in)[(size_t)i * 2 + 1];
  u16x8 r;
  r[0] = f2b(v0.x); r[1] = f2b(v0.y); r[2] = f2b(v0.z); r[3] = f2b(v0.w);
  r[4] = f2b(v1.x); r[5] = f2b(v1.y); r[6] = f2b(v1.z); r[7] = f2b(v1.w);
  *(u16x8*)(out + (size_t)i * 8) = r;
}

// in[R][C] fp32 -> out[C][R] bf16
__global__ __launch_bounds__(256) void transpose_cvt(const float* __restrict__ in,
                                                     u16* __restrict__ out, int R, int C) {
  __shared__ float tile[32][33];
  int nbx = C >> 5;
  int bx = blockIdx.x % nbx, by = blockIdx.x / nbx;
  int tx = threadIdx.x & 31, ty = threadIdx.x >> 5;  // 32 x 8
#pragma unroll
  for (int jj = 0; jj < 32; jj += 8)
    tile[ty + jj][tx] = in[(size_t)(by * 32 + ty + jj) * C + bx * 32 + tx];
  __syncthreads();
#pragma unroll
  for (int jj = 0; jj < 32; jj += 8)
    out[(size_t)(bx * 32 + ty + jj) * R + by * 32 + tx] = f2b(tile[tx][ty + jj]);
}

// ---------------- GEMM: C[M][N] = A[M][K] @ Bt[N][K]^T + bias ----------------
// EPI=0: store bf16 (qkv buffer). EPI=1: store fp32 (final output).
// 128x128 tile, BK=32, 256 threads (4 waves, 2x2), each wave 64x64 = 4x4 MFMA tiles.

template <int EPI>
__global__ __launch_bounds__(256) void gemm_bt(const u16* __restrict__ A,
                                               const u16* __restrict__ Bt,
                                               const float* __restrict__ bias,
                                               void* __restrict__ out,
                                               int M, int N, int K) {
  __shared__ __align__(16) u16 As[128 * 32];
  __shared__ __align__(16) u16 Bs[128 * 32];
  const int t = threadIdx.x;
  const int l = t & 63;
  const int w = t >> 6;
  const int wr = w >> 1, wc = w & 1;
  const int lm = l & 15, g = l >> 4;
  const int nbx = N >> 7;
  const int brow = (blockIdx.x / nbx) << 7;
  const int bcol = (blockIdx.x % nbx) << 7;

  f32x4 acc[4][4] = {};

  // staging: thread covers row r = t/4 (+64 for second issue), chunk c0 = t%4 of 4x8-elem chunks.
  // XOR swizzle on SOURCE chunk (global) + same XOR on read slot (rule #21 both-sides).
  const int r0 = t >> 2;
  const int c0 = t & 3;
  const int swz0 = (c0 ^ ((r0 >> 1) & 3)) * 8;  // same for r0 and r0+64 (64/2 % 4 == 0)
  const u16* gA0 = A + (size_t)(brow + r0) * K + swz0;
  const u16* gA1 = A + (size_t)(brow + r0 + 64) * K + swz0;
  const u16* gB0 = Bt + (size_t)(bcol + r0) * K + swz0;
  const u16* gB1 = Bt + (size_t)(bcol + r0 + 64) * K + swz0;
  u16* lA0 = As + t * 8;
  u16* lA1 = As + (t + 256) * 8;
  u16* lB0 = Bs + t * 8;
  u16* lB1 = Bs + (t + 256) * 8;

  const int KT = K >> 5;
  for (int kt = 0; kt < KT; ++kt) {
    const int k0 = kt << 5;
    __syncthreads();
    gload_lds16(gA0 + k0, lA0);
    gload_lds16(gA1 + k0, lA1);
    gload_lds16(gB0 + k0, lB0);
    gload_lds16(gB1 + k0, lB1);
    __syncthreads();
    bf16x8 af[4], bf_[4];
#pragma unroll
    for (int m = 0; m < 4; ++m) {
      int r = wr * 64 + m * 16 + lm;
      af[m] = lds_read16(As + r * 32 + ((g ^ ((r >> 1) & 3)) * 8));
    }
#pragma unroll
    for (int n = 0; n < 4; ++n) {
      int r = wc * 64 + n * 16 + lm;
      bf_[n] = lds_read16(Bs + r * 32 + ((g ^ ((r >> 1) & 3)) * 8));
    }
#pragma unroll
    for (int m = 0; m < 4; ++m)
#pragma unroll
      for (int n = 0; n < 4; ++n)
        acc[m][n] = __builtin_amdgcn_mfma_f32_16x16x32_bf16(af[m], bf_[n], acc[m][n], 0, 0, 0);
  }

#pragma unroll
  for (int n = 0; n < 4; ++n) {
    int c = bcol + wc * 64 + n * 16 + lm;
    float bv = bias[c];
#pragma unroll
    for (int m = 0; m < 4; ++m) {
      int rbase = brow + wr * 64 + m * 16 + g * 4;
#pragma unroll
      for (int j = 0; j < 4; ++j) {
        float v = acc[m][n][j] + bv;
        if (EPI == 0)
          ((u16*)out)[(size_t)(rbase + j) * N + c] = f2b(v);
        else
          ((float*)out)[(size_t)(rbase + j) * N + c] = v;
      }
    }
  }
}

// ---------------- fused flash attention ----------------
// qkv: [8192][2304] bf16 rows = (b,t), cols: [0,768)=Q [768,1536)=K [1536,2304)=V, per-head 64.
// grid: (b,h,qtile64) = 16*12*8 = 1536 blocks, 256 threads (4 waves), wave owns 16 q-rows.
// out: [8192][768] bf16 = (b,t) x (h,d).

__global__ __launch_bounds__(256) void attn_fused(const u16* __restrict__ qkv,
                                                  const int* __restrict__ mask,
                                                  u16* __restrict__ out) {
  __shared__ __align__(16) u16 Ks[64 * 64];       // [key][d], swizzled 16B chunks
  __shared__ __align__(16) u16 Vs[64 * 64];       // [d][key] (transposed), swizzled
  __shared__ __align__(16) u16 Ps[4][16 * 64];    // per-wave P [q16][key64], swizzled

  const int t = threadIdx.x, l = t & 63, w = t >> 6;
  const int lm = l & 15, g = l >> 4;
  const int bid = blockIdx.x;
  const int qt = bid & 7;
  const int bh = bid >> 3;
  const int b = bh / 12, h = bh % 12;

  // Q fragments held in registers for the whole kernel (reused across all K tiles)
  bf16x8 qf[2];
  {
    const u16* qptr = qkv + (size_t)(b * 512 + qt * 64 + w * 16 + lm) * 2304 + h * 64;
    qf[0] = *(const bf16x8*)(qptr + g * 8);
    qf[1] = *(const bf16x8*)(qptr + 32 + g * 8);
  }

  f32x4 o[4] = {};
  float mrun[4], lrun[4];
#pragma unroll
  for (int j = 0; j < 4; ++j) { mrun[j] = -3.0e38f; lrun[j] = 0.f; }

  const int rk = t >> 3;  // 0..31 (row within half-tile)
  const int ck = t & 7;   // chunk 0..7

  for (int kt = 0; kt < 8; ++kt) {
    __syncthreads();
    const size_t rowK = (size_t)(b * 512 + kt * 64);
    // stage K tile [64][64] via global_load_lds, source-swizzled chunks
#pragma unroll
    for (int i = 0; i < 2; ++i) {
      int r = rk + 32 * i;
      int c = ck ^ (r & 7);
      gload_lds16(qkv + (rowK + r) * 2304 + 768 + h * 64 + c * 8, Ks + (t + 256 * i) * 8);
    }
    // stage V transposed: Vs[d][key], swizzled on row d
#pragma unroll
    for (int i = 0; i < 2; ++i) {
      int key = rk + 32 * i;
      int d0 = ck * 8;
      u16x8 v = *(const u16x8*)(qkv + (rowK + key) * 2304 + 1536 + h * 64 + d0);
#pragma unroll
      for (int jj = 0; jj < 8; ++jj) {
        int d = d0 + jj;
        Vs[d * 64 + (((key >> 3) ^ (d & 7)) * 8) + (key & 7)] = v[jj];
      }
    }
    __syncthreads();

    // S = Q K^T  (wave: 16 q x 64 keys)
    f32x4 s[4] = {};
#pragma unroll
    for (int ds = 0; ds < 2; ++ds) {
#pragma unroll
      for (int n = 0; n < 4; ++n) {
        int r = n * 16 + lm;
        bf16x8 kf = lds_read16(Ks + r * 64 + (((ds * 4 + g) ^ (r & 7)) * 8));
        s[n] = __builtin_amdgcn_mfma_f32_16x16x32_bf16(qf[ds], kf, s[n], 0, 0, 0);
      }
    }
    // scale 1/sqrt(64) and mask (mask==0 -> -inf). mask buffer is int32 per harness.
#pragma unroll
    for (int n = 0; n < 4; ++n) {
      int mk = mask[b * 512 + kt * 64 + n * 16 + lm];
#pragma unroll
      for (int j = 0; j < 4; ++j) {
        float sv = s[n][j] * 0.125f;
        s[n][j] = (mk == 0) ? -3.0e38f : sv;
      }
    }
    // online softmax; lane's rows are q16 = g*4+j, row spread over 16 lanes (lm) x 4 regs (n)
    float alpha[4];
#pragma unroll
    for (int j = 0; j < 4; ++j) {
      float rmax = fmaxf(fmaxf(s[0][j], s[1][j]), fmaxf(s[2][j], s[3][j]));
#pragma unroll
      for (int off = 8; off >= 1; off >>= 1) rmax = fmaxf(rmax, __shfl_xor(rmax, off));
      float mnew = fmaxf(mrun[j], rmax);
      alpha[j] = __expf(mrun[j] - mnew);
      mrun[j] = mnew;
      float rsum = 0.f;
#pragma unroll
      for (int n = 0; n < 4; ++n) {
        float p = __expf(s[n][j] - mnew);
        s[n][j] = p;
        rsum += p;
      }
#pragma unroll
      for (int off = 8; off >= 1; off >>= 1) rsum += __shfl_xor(rsum, off);
      lrun[j] = lrun[j] * alpha[j] + rsum;
    }
#pragma unroll
    for (int n = 0; n < 4; ++n)
#pragma unroll
      for (int j = 0; j < 4; ++j) o[n][j] *= alpha[j];

    // P -> per-wave LDS (bf16, swizzled), then PV MFMA
    u16* pw = Ps[w];
#pragma unroll
    for (int n = 0; n < 4; ++n) {
      int key = n * 16 + lm;
#pragma unroll
      for (int j = 0; j < 4; ++j) {
        int q16 = g * 4 + j;
        pw[q16 * 64 + (((key >> 3) ^ (q16 & 7)) * 8) + (key & 7)] = f2b(s[n][j]);
      }
    }
#pragma unroll
    for (int ks = 0; ks < 2; ++ks) {
      bf16x8 pa = lds_read16(pw + lm * 64 + (((ks * 4 + g) ^ (lm & 7)) * 8));
#pragma unroll
      for (int n = 0; n < 4; ++n) {
        int rd = n * 16 + lm;
        bf16x8 vb = lds_read16(Vs + rd * 64 + (((ks * 4 + g) ^ (rd & 7)) * 8));
        o[n] = __builtin_amdgcn_mfma_f32_16x16x32_bf16(pa, vb, o[n], 0, 0, 0);
      }
    }
  }

  // epilogue: normalize and store bf16 to (b,t) x (h,d)
  float inv[4];
#pragma unroll
  for (int j = 0; j < 4; ++j) inv[j] = 1.0f / lrun[j];
#pragma unroll
  for (int n = 0; n < 4; ++n) {
    int d = n * 16 + lm;
#pragma unroll
    for (int j = 0; j < 4; ++j) {
      int tq = qt * 64 + w * 16 + g * 4 + j;
      out[(size_t)(b * 512 + tq) * 768 + h * 64 + d] = f2b(o[n][j] * inv[j]);
    }
  }
}

// ---------------- launch ----------------

extern "C" void kernel_launch(void* const* d_in, const int* in_sizes, int n_in,
                              void* d_out, int out_size, void* d_ws, size_t ws_size,
                              hipStream_t stream) {
  const float* x = (const float*)d_in[0];
  const int* mask = (const int*)d_in[1];  // harness delivers integer inputs as int32
  const float* Wqkv = (const float*)d_in[2];
  const float* bqkv = (const float*)d_in[3];
  const float* Wproj = (const float*)d_in[4];
  const float* bproj = (const float*)d_in[5];
  float* out = (float*)d_out;

  char* ws = (char*)d_ws;
  u16* xb     = (u16*)(ws);                    // 8192*768*2   = 12,582,912
  u16* wqkvT  = (u16*)(ws + 12582912);         // 2304*768*2   =  3,538,944
  u16* wprojT = (u16*)(ws + 16121856);         // 768*768*2    =  1,179,648
  u16* qkvb   = (u16*)(ws + 17301504);         // 8192*2304*2  = 37,748,736
  u16* attnb  = (u16*)(ws + 55050240);         // 8192*768*2   = 12,582,912  (end 67,633,152)

  cvt_x<<<3072, 256, 0, stream>>>(x, xb, 786432);
  transpose_cvt<<<72 * 24, 256, 0, stream>>>(Wqkv, wqkvT, 768, 2304);
  transpose_cvt<<<24 * 24, 256, 0, stream>>>(Wproj, wprojT, 768, 768);
  gemm_bt<0><<<64 * 18, 256, 0, stream>>>(xb, wqkvT, bqkv, qkvb, 8192, 2304, 768);
  attn_fused<<<1536, 256, 0, stream>>>(qkvb, mask, attnb);
  gemm_bt<1><<<64 * 6, 256, 0, stream>>>(attnb, wprojT, bproj, out, 8192, 768, 768);
}

// Round 3
// 145.424 us; speedup vs baseline: 1.0625x; 1.0625x over previous
//
#include <hip/hip_runtime.h>

// Fused attention block: qkv = x@Wqkv+b; per-head softmax(QK^T/8)V; y = att@Wproj+b
// B=16 T=512 H=768 NH=12 HS=64. All GEMM/attn compute in bf16 MFMA (16x16x32), fp32 accum.
// R2: V written pre-transposed by qkv GEMM epilogue (Vt[b,h][d][t]); attn stages K,V via
//     linear gload_lds with 2-phase double-buffer prefetch; gemm_bt also 2-phase.

typedef unsigned short u16;
typedef __bf16 bf16x8 __attribute__((ext_vector_type(8)));
typedef float f32x4 __attribute__((ext_vector_type(4)));
typedef unsigned short u16x8 __attribute__((ext_vector_type(8)));

__device__ __forceinline__ u16 f2b(float f) {
  union { float f; unsigned int u; } v; v.f = f;
  unsigned int u = v.u;
  return (u16)((u + 0x7FFFu + ((u >> 16) & 1u)) >> 16);  // RNE
}

__device__ __forceinline__ void gload_lds16(const u16* gsrc, u16* ldst) {
  __builtin_amdgcn_global_load_lds(
      (const __attribute__((address_space(1))) void*)gsrc,
      (__attribute__((address_space(3))) void*)ldst,
      16, 0, 0);
}

__device__ __forceinline__ bf16x8 lds_read16(const u16* p) {
  return __builtin_bit_cast(bf16x8, *(const int4*)p);
}

// ---------------- converts ----------------

__global__ __launch_bounds__(256) void cvt_x(const float* __restrict__ in,
                                             u16* __restrict__ out, int n8) {
  int i = blockIdx.x * 256 + threadIdx.x;
  if (i >= n8) return;
  float4 v0 = ((const float4*)in)[(size_t)i * 2];
  float4 v1 = ((const float4*)in)[(size_t)i * 2 + 1];
  u16x8 r;
  r[0] = f2b(v0.x); r[1] = f2b(v0.y); r[2] = f2b(v0.z); r[3] = f2b(v0.w);
  r[4] = f2b(v1.x); r[5] = f2b(v1.y); r[6] = f2b(v1.z); r[7] = f2b(v1.w);
  *(u16x8*)(out + (size_t)i * 8) = r;
}

// in[R][C] fp32 -> out[C][R] bf16
__global__ __launch_bounds__(256) void transpose_cvt(const float* __restrict__ in,
                                                     u16* __restrict__ out, int R, int C) {
  __shared__ float tile[32][33];
  int nbx = C >> 5;
  int bx = blockIdx.x % nbx, by = blockIdx.x / nbx;
  int tx = threadIdx.x & 31, ty = threadIdx.x >> 5;  // 32 x 8
#pragma unroll
  for (int jj = 0; jj < 32; jj += 8)
    tile[ty + jj][tx] = in[(size_t)(by * 32 + ty + jj) * C + bx * 32 + tx];
  __syncthreads();
#pragma unroll
  for (int jj = 0; jj < 32; jj += 8)
    out[(size_t)(bx * 32 + ty + jj) * R + by * 32 + tx] = f2b(tile[tx][ty + jj]);
}

// ---------------- GEMM: C[M][N] = A[M][K] @ Bt[N][K]^T + bias ----------------
// MODE 0: qkv GEMM. cols <1536 -> bf16 to out (stride 1536); cols >=1536 (V) -> bf16
//         TRANSPOSED to vt[b,h][d][t].   MODE 1: fp32 to out (stride N).
// 128x128 tile, BK=32, 256 threads (4 waves, 2x2), wave 64x64 = 4x4 MFMA tiles.
// 2-phase double-buffered LDS: stage(kt+1) issued before compute(kt), one barrier/iter.

template <int MODE>
__global__ __launch_bounds__(256) void gemm_bt(const u16* __restrict__ A,
                                               const u16* __restrict__ Bt,
                                               const float* __restrict__ bias,
                                               void* __restrict__ out,
                                               u16* __restrict__ vt,
                                               int M, int N, int K) {
  __shared__ __align__(16) u16 As[2][128 * 32];
  __shared__ __align__(16) u16 Bs[2][128 * 32];
  const int t = threadIdx.x;
  const int l = t & 63;
  const int w = t >> 6;
  const int wr = w >> 1, wc = w & 1;
  const int lm = l & 15, g = l >> 4;
  const int nbx = N >> 7;
  const int brow = (blockIdx.x / nbx) << 7;
  const int bcol = (blockIdx.x % nbx) << 7;

  f32x4 acc[4][4] = {};

  // staging: thread covers row r0 = t/4 (+64 second issue), chunk c0 = t%4.
  // XOR swizzle on SOURCE chunk + same XOR on read slot (both-sides, rule #21).
  const int r0 = t >> 2;
  const int c0 = t & 3;
  const int swz0 = (c0 ^ ((r0 >> 1) & 3)) * 8;  // same for r0 and r0+64
  const u16* gA0 = A + (size_t)(brow + r0) * K + swz0;
  const u16* gA1 = A + (size_t)(brow + r0 + 64) * K + swz0;
  const u16* gB0 = Bt + (size_t)(bcol + r0) * K + swz0;
  const u16* gB1 = Bt + (size_t)(bcol + r0 + 64) * K + swz0;

  const int KT = K >> 5;
  auto stage = [&](int kt, int buf) {
    const int k0 = kt << 5;
    gload_lds16(gA0 + k0, As[buf] + t * 8);
    gload_lds16(gA1 + k0, As[buf] + (t + 256) * 8);
    gload_lds16(gB0 + k0, Bs[buf] + t * 8);
    gload_lds16(gB1 + k0, Bs[buf] + (t + 256) * 8);
  };

  stage(0, 0);
  __syncthreads();  // vmcnt(0)+lgkmcnt(0)+barrier: buf0 ready
  int cur = 0;
  for (int kt = 0; kt < KT; ++kt) {
    if (kt + 1 < KT) stage(kt + 1, cur ^ 1);  // prefetch overlaps compute below
    bf16x8 af[4], bf_[4];
#pragma unroll
    for (int m = 0; m < 4; ++m) {
      int r = wr * 64 + m * 16 + lm;
      af[m] = lds_read16(As[cur] + r * 32 + ((g ^ ((r >> 1) & 3)) * 8));
    }
#pragma unroll
    for (int n = 0; n < 4; ++n) {
      int r = wc * 64 + n * 16 + lm;
      bf_[n] = lds_read16(Bs[cur] + r * 32 + ((g ^ ((r >> 1) & 3)) * 8));
    }
#pragma unroll
    for (int m = 0; m < 4; ++m)
#pragma unroll
      for (int n = 0; n < 4; ++n)
        acc[m][n] = __builtin_amdgcn_mfma_f32_16x16x32_bf16(af[m], bf_[n], acc[m][n], 0, 0, 0);
    __syncthreads();  // drains prefetch vmcnt + all waves done reading cur
    cur ^= 1;
  }

  if (MODE == 0 && bcol >= 1536) {
    // V columns -> transposed store: vt[((b*12+h)*64+d)*512 + t], 4 consecutive t per thread
    const int b = brow >> 9;  // 128-row block lies within one 512-row batch
#pragma unroll
    for (int n = 0; n < 4; ++n) {
      int cv = bcol - 1536 + wc * 64 + n * 16 + lm;
      int hh = cv >> 6, dd = cv & 63;
      float bv = bias[cv + 1536];
      u16* vrow = vt + (((size_t)(b * 12 + hh) * 64 + dd) << 9);
#pragma unroll
      for (int m = 0; m < 4; ++m) {
        int tq = (brow + wr * 64 + m * 16 + g * 4) & 511;
        ushort4 pk;
        pk.x = f2b(acc[m][n][0] + bv);
        pk.y = f2b(acc[m][n][1] + bv);
        pk.z = f2b(acc[m][n][2] + bv);
        pk.w = f2b(acc[m][n][3] + bv);
        *(ushort4*)(vrow + tq) = pk;
      }
    }
  } else {
#pragma unroll
    for (int n = 0; n < 4; ++n) {
      int c = bcol + wc * 64 + n * 16 + lm;
      float bv = bias[c];
#pragma unroll
      for (int m = 0; m < 4; ++m) {
        int rbase = brow + wr * 64 + m * 16 + g * 4;
#pragma unroll
        for (int j = 0; j < 4; ++j) {
          float v = acc[m][n][j] + bv;
          if (MODE == 0)
            ((u16*)out)[(size_t)(rbase + j) * 1536 + c] = f2b(v);
          else
            ((float*)out)[(size_t)(rbase + j) * N + c] = v;
        }
      }
    }
  }
}

// ---------------- fused flash attention ----------------
// qk: [8192][1536] bf16, cols [0,768)=Q [768,1536)=K. vt: [192][64][512] bf16 (d-major V).
// grid: (b,h,qtile64) = 1536 blocks, 256 threads (4 waves), wave owns 16 q-rows.
// K and V tiles double-buffered in LDS via linear gload_lds (source-chunk XOR swizzle).

__global__ __launch_bounds__(256) void attn_fused(const u16* __restrict__ qk,
                                                  const u16* __restrict__ vt,
                                                  const int* __restrict__ mask,
                                                  u16* __restrict__ out) {
  __shared__ __align__(16) u16 Ks[2][64 * 64];     // [key][d], swizzled 16B chunks
  __shared__ __align__(16) u16 Vs[2][64 * 64];     // [d][key], swizzled 16B chunks
  __shared__ __align__(16) u16 Ps[4][16 * 64];     // per-wave P [q16][key64], swizzled

  const int t = threadIdx.x, l = t & 63, w = t >> 6;
  const int lm = l & 15, g = l >> 4;
  const int bid = blockIdx.x;
  const int qt = bid & 7;
  const int bh = bid >> 3;
  const int b = bh / 12, h = bh % 12;

  // Q fragments in registers for the whole kernel
  bf16x8 qf[2];
  {
    const u16* qptr = qk + (size_t)(b * 512 + qt * 64 + w * 16 + lm) * 1536 + h * 64;
    qf[0] = *(const bf16x8*)(qptr + g * 8);
    qf[1] = *(const bf16x8*)(qptr + 32 + g * 8);
  }

  f32x4 o[4] = {};
  float mrun[4], lrun[4];
#pragma unroll
  for (int j = 0; j < 4; ++j) { mrun[j] = -3.0e38f; lrun[j] = 0.f; }

  // staging addresses: thread covers row rk (and rk+32), chunk ck of 8; source chunk
  // XOR-swizzled so LDS[r][c] holds source chunk c^(r&7)  (rk+32 keeps same swizzle).
  const int rk = t >> 3, ck = t & 7;
  const int cswz = ck ^ (rk & 7);
  const u16* srcK = qk + (size_t)(b * 512 + rk) * 1536 + 768 + h * 64 + cswz * 8;
  const u16* srcV = vt + ((size_t)(bh * 64 + rk)) * 512 + cswz * 8;

  auto stage = [&](int kt, int buf) {
    const size_t offK = (size_t)kt * 64 * 1536;
    gload_lds16(srcK + offK, Ks[buf] + t * 8);
    gload_lds16(srcK + offK + 32 * 1536, Ks[buf] + (t + 256) * 8);
    gload_lds16(srcV + kt * 64, Vs[buf] + t * 8);
    gload_lds16(srcV + kt * 64 + 32 * 512, Vs[buf] + (t + 256) * 8);
  };

  stage(0, 0);
  __syncthreads();
  int cur = 0;

  for (int kt = 0; kt < 8; ++kt) {
    if (kt < 7) stage(kt + 1, cur ^ 1);  // prefetch next K/V tile

    // S = Q K^T  (wave: 16 q x 64 keys)
    f32x4 s[4] = {};
#pragma unroll
    for (int ds = 0; ds < 2; ++ds) {
#pragma unroll
      for (int n = 0; n < 4; ++n) {
        int r = n * 16 + lm;
        bf16x8 kf = lds_read16(Ks[cur] + r * 64 + (((ds * 4 + g) ^ (r & 7)) * 8));
        s[n] = __builtin_amdgcn_mfma_f32_16x16x32_bf16(qf[ds], kf, s[n], 0, 0, 0);
      }
    }
    // scale 1/sqrt(64) and mask (mask==0 -> -inf); mask is int32 per harness
#pragma unroll
    for (int n = 0; n < 4; ++n) {
      int mk = mask[b * 512 + kt * 64 + n * 16 + lm];
#pragma unroll
      for (int j = 0; j < 4; ++j) {
        float sv = s[n][j] * 0.125f;
        s[n][j] = (mk == 0) ? -3.0e38f : sv;
      }
    }
    // online softmax; lane's rows are q16 = g*4+j, row spread over 16 lanes (lm) x 4 regs (n)
    float alpha[4];
#pragma unroll
    for (int j = 0; j < 4; ++j) {
      float rmax = fmaxf(fmaxf(s[0][j], s[1][j]), fmaxf(s[2][j], s[3][j]));
#pragma unroll
      for (int off = 8; off >= 1; off >>= 1) rmax = fmaxf(rmax, __shfl_xor(rmax, off));
      float mnew = fmaxf(mrun[j], rmax);
      alpha[j] = __expf(mrun[j] - mnew);
      mrun[j] = mnew;
      float rsum = 0.f;
#pragma unroll
      for (int n = 0; n < 4; ++n) {
        float p = __expf(s[n][j] - mnew);
        s[n][j] = p;
        rsum += p;
      }
#pragma unroll
      for (int off = 8; off >= 1; off >>= 1) rsum += __shfl_xor(rsum, off);
      lrun[j] = lrun[j] * alpha[j] + rsum;
    }
#pragma unroll
    for (int n = 0; n < 4; ++n)
#pragma unroll
      for (int j = 0; j < 4; ++j) o[n][j] *= alpha[j];

    // P -> per-wave LDS (bf16, swizzled), then PV MFMA
    u16* pw = Ps[w];
#pragma unroll
    for (int n = 0; n < 4; ++n) {
      int key = n * 16 + lm;
#pragma unroll
      for (int j = 0; j < 4; ++j) {
        int q16 = g * 4 + j;
        pw[q16 * 64 + (((key >> 3) ^ (q16 & 7)) * 8) + (key & 7)] = f2b(s[n][j]);
      }
    }
#pragma unroll
    for (int ks = 0; ks < 2; ++ks) {
      bf16x8 pa = lds_read16(pw + lm * 64 + (((ks * 4 + g) ^ (lm & 7)) * 8));
#pragma unroll
      for (int n = 0; n < 4; ++n) {
        int rd = n * 16 + lm;
        bf16x8 vb = lds_read16(Vs[cur] + rd * 64 + (((ks * 4 + g) ^ (rd & 7)) * 8));
        o[n] = __builtin_amdgcn_mfma_f32_16x16x32_bf16(pa, vb, o[n], 0, 0, 0);
      }
    }
    __syncthreads();  // drains prefetch + all waves done with Ks/Vs[cur]
    cur ^= 1;
  }

  // epilogue: normalize and store bf16 to (b,t) x (h,d)
  float inv[4];
#pragma unroll
  for (int j = 0; j < 4; ++j) inv[j] = 1.0f / lrun[j];
#pragma unroll
  for (int n = 0; n < 4; ++n) {
    int d = n * 16 + lm;
#pragma unroll
    for (int j = 0; j < 4; ++j) {
      int tq = qt * 64 + w * 16 + g * 4 + j;
      out[(size_t)(b * 512 + tq) * 768 + h * 64 + d] = f2b(o[n][j] * inv[j]);
    }
  }
}

// ---------------- launch ----------------

extern "C" void kernel_launch(void* const* d_in, const int* in_sizes, int n_in,
                              void* d_out, int out_size, void* d_ws, size_t ws_size,
                              hipStream_t stream) {
  const float* x = (const float*)d_in[0];
  const int* mask = (const int*)d_in[1];  // harness delivers integer inputs as int32
  const float* Wqkv = (const float*)d_in[2];
  const float* bqkv = (const float*)d_in[3];
  const float* Wproj = (const float*)d_in[4];
  const float* bproj = (const float*)d_in[5];
  float* out = (float*)d_out;

  char* ws = (char*)d_ws;
  u16* xb     = (u16*)(ws);                    // 8192*768*2   = 12,582,912
  u16* wqkvT  = (u16*)(ws + 12582912);         // 2304*768*2   =  3,538,944
  u16* wprojT = (u16*)(ws + 16121856);         // 768*768*2    =  1,179,648
  u16* qkb    = (u16*)(ws + 17301504);         // 8192*1536*2  = 25,165,824
  u16* vtb    = (u16*)(ws + 42467328);         // 192*64*512*2 = 12,582,912
  u16* attnb  = (u16*)(ws + 55050240);         // 8192*768*2   = 12,582,912  (end 67,633,152)

  cvt_x<<<3072, 256, 0, stream>>>(x, xb, 786432);
  transpose_cvt<<<72 * 24, 256, 0, stream>>>(Wqkv, wqkvT, 768, 2304);
  transpose_cvt<<<24 * 24, 256, 0, stream>>>(Wproj, wprojT, 768, 768);
  gemm_bt<0><<<64 * 18, 256, 0, stream>>>(xb, wqkvT, bqkv, qkb, vtb, 8192, 2304, 768);
  attn_fused<<<1536, 256, 0, stream>>>(qkb, vtb, mask, attnb);
  gemm_bt<1><<<64 * 6, 256, 0, stream>>>(attnb, wprojT, bproj, out, nullptr, 8192, 768, 768);
}

// Round 4
// 141.058 us; speedup vs baseline: 1.0954x; 1.0310x over previous
//
#include <hip/hip_runtime.h>

// Fused attention block: qkv = x@Wqkv+b; per-head softmax(QK^T/8)V; y = att@Wproj+b
// B=16 T=512 H=768 NH=12 HS=64. All GEMM/attn compute in bf16 MFMA (16x16x32), fp32 accum.
// R3: T1 chunked XCD swizzle (all hot kernels); gemm depth-3 pipeline with counted
//     s_waitcnt vmcnt(4) (never 0 in steady state); attn mask hoisted to bitmask so
//     the K/V prefetch is never drained by in-loop vmem.

typedef unsigned short u16;
typedef __bf16 bf16x8 __attribute__((ext_vector_type(8)));
typedef float f32x4 __attribute__((ext_vector_type(4)));
typedef unsigned short u16x8 __attribute__((ext_vector_type(8)));

__device__ __forceinline__ u16 f2b(float f) {
  union { float f; unsigned int u; } v; v.f = f;
  unsigned int u = v.u;
  return (u16)((u + 0x7FFFu + ((u >> 16) & 1u)) >> 16);  // RNE
}

__device__ __forceinline__ void gload_lds16(const u16* gsrc, u16* ldst) {
  __builtin_amdgcn_global_load_lds(
      (const __attribute__((address_space(1))) void*)gsrc,
      (__attribute__((address_space(3))) void*)ldst,
      16, 0, 0);
}

__device__ __forceinline__ bf16x8 lds_read16(const u16* p) {
  return __builtin_bit_cast(bf16x8, *(const int4*)p);
}

__device__ __forceinline__ int inc3(int x) { return x == 2 ? 0 : x + 1; }

// ---------------- converts ----------------

__global__ __launch_bounds__(256) void cvt_x(const float* __restrict__ in,
                                             u16* __restrict__ out, int n8) {
  int i = blockIdx.x * 256 + threadIdx.x;
  if (i >= n8) return;
  float4 v0 = ((const float4*)in)[(size_t)i * 2];
  float4 v1 = ((const float4*)in)[(size_t)i * 2 + 1];
  u16x8 r;
  r[0] = f2b(v0.x); r[1] = f2b(v0.y); r[2] = f2b(v0.z); r[3] = f2b(v0.w);
  r[4] = f2b(v1.x); r[5] = f2b(v1.y); r[6] = f2b(v1.z); r[7] = f2b(v1.w);
  *(u16x8*)(out + (size_t)i * 8) = r;
}

// in[R][C] fp32 -> out[C][R] bf16
__global__ __launch_bounds__(256) void transpose_cvt(const float* __restrict__ in,
                                                     u16* __restrict__ out, int R, int C) {
  __shared__ float tile[32][33];
  int nbx = C >> 5;
  int bx = blockIdx.x % nbx, by = blockIdx.x / nbx;
  int tx = threadIdx.x & 31, ty = threadIdx.x >> 5;  // 32 x 8
#pragma unroll
  for (int jj = 0; jj < 32; jj += 8)
    tile[ty + jj][tx] = in[(size_t)(by * 32 + ty + jj) * C + bx * 32 + tx];
  __syncthreads();
#pragma unroll
  for (int jj = 0; jj < 32; jj += 8)
    out[(size_t)(bx * 32 + ty + jj) * R + by * 32 + tx] = f2b(tile[tx][ty + jj]);
}

// ---------------- GEMM: C[M][N] = A[M][K] @ Bt[N][K]^T + bias ----------------
// MODE 0: qkv GEMM. cols <1536 -> bf16 to out (stride 1536); cols >=1536 (V) -> bf16
//         TRANSPOSED to vt[b,h][d][t].   MODE 1: fp32 to out (stride N).
// 128x128 tile, BK=32, 256 threads (4 waves, 2x2), wave 64x64 = 4x4 MFMA tiles.
// Depth-3 pipeline: stage(kt+2) issued at top; end-of-iter waits vmcnt(4) (the
// NEXT tile's loads), never draining the newest prefetch. One barrier/iter.

template <int MODE>
__global__ __launch_bounds__(256) void gemm_bt(const u16* __restrict__ A,
                                               const u16* __restrict__ Bt,
                                               const float* __restrict__ bias,
                                               void* __restrict__ out,
                                               u16* __restrict__ vt,
                                               int M, int N, int K) {
  __shared__ __align__(16) u16 As[3][128 * 32];
  __shared__ __align__(16) u16 Bs[3][128 * 32];
  const int t = threadIdx.x;
  const int l = t & 63;
  const int w = t >> 6;
  const int wr = w >> 1, wc = w & 1;
  const int lm = l & 15, g = l >> 4;
  const int nbx = N >> 7;
  // T1: chunked XCD remap (gridDim.x % 8 == 0 -> bijective). Consecutive logical
  // tiles (sharing A row-panels) land on the same XCD's L2.
  const int cpx = gridDim.x >> 3;
  const int bid = (blockIdx.x & 7) * cpx + (blockIdx.x >> 3);
  const int brow = (bid / nbx) << 7;
  const int bcol = (bid % nbx) << 7;

  f32x4 acc[4][4] = {};

  // staging: thread covers row r0 = t/4 (+64 second issue), chunk c0 = t%4.
  // XOR swizzle on SOURCE chunk + same XOR on read slot (both-sides, rule #21).
  const int r0 = t >> 2;
  const int c0 = t & 3;
  const int swz0 = (c0 ^ ((r0 >> 1) & 3)) * 8;  // same for r0 and r0+64
  const u16* gA0 = A + (size_t)(brow + r0) * K + swz0;
  const u16* gA1 = A + (size_t)(brow + r0 + 64) * K + swz0;
  const u16* gB0 = Bt + (size_t)(bcol + r0) * K + swz0;
  const u16* gB1 = Bt + (size_t)(bcol + r0 + 64) * K + swz0;

  const int KT = K >> 5;
  auto stage = [&](int kt, int buf) {
    const int k0 = kt << 5;
    gload_lds16(gA0 + k0, As[buf] + t * 8);
    gload_lds16(gA1 + k0, As[buf] + (t + 256) * 8);
    gload_lds16(gB0 + k0, Bs[buf] + t * 8);
    gload_lds16(gB1 + k0, Bs[buf] + (t + 256) * 8);
  };

  stage(0, 0);
  stage(1, 1);
  asm volatile("s_waitcnt vmcnt(4)" ::: "memory");  // buf0's 4 loads done; buf1 in flight
  __builtin_amdgcn_s_barrier();
  __builtin_amdgcn_sched_barrier(0);

  int cur = 0, pre = 2;  // pre = (kt+2)%3
  for (int kt = 0; kt < KT; ++kt) {
    if (kt + 2 < KT) stage(kt + 2, pre);  // overwrites buf consumed in kt-1 (safe post-barrier)
    bf16x8 af[4], bf_[4];
#pragma unroll
    for (int m = 0; m < 4; ++m) {
      int r = wr * 64 + m * 16 + lm;
      af[m] = lds_read16(As[cur] + r * 32 + ((g ^ ((r >> 1) & 3)) * 8));
    }
#pragma unroll
    for (int n = 0; n < 4; ++n) {
      int r = wc * 64 + n * 16 + lm;
      bf_[n] = lds_read16(Bs[cur] + r * 32 + ((g ^ ((r >> 1) & 3)) * 8));
    }
#pragma unroll
    for (int m = 0; m < 4; ++m)
#pragma unroll
      for (int n = 0; n < 4; ++n)
        acc[m][n] = __builtin_amdgcn_mfma_f32_16x16x32_bf16(af[m], bf_[n], acc[m][n], 0, 0, 0);
    // wait only for the NEXT buffer's loads (issued last iter); newest stay in flight
    __builtin_amdgcn_sched_barrier(0);
    if (kt + 2 < KT) {
      asm volatile("s_waitcnt vmcnt(4)" ::: "memory");
    } else {
      asm volatile("s_waitcnt vmcnt(0)" ::: "memory");
    }
    __builtin_amdgcn_s_barrier();
    __builtin_amdgcn_sched_barrier(0);
    cur = inc3(cur);
    pre = inc3(pre);
  }

  if (MODE == 0 && bcol >= 1536) {
    // V columns -> transposed store: vt[((b*12+h)*64+d)*512 + t], 4 consecutive t per thread
    const int b = brow >> 9;  // 128-row block lies within one 512-row batch
#pragma unroll
    for (int n = 0; n < 4; ++n) {
      int cv = bcol - 1536 + wc * 64 + n * 16 + lm;
      int hh = cv >> 6, dd = cv & 63;
      float bv = bias[cv + 1536];
      u16* vrow = vt + (((size_t)(b * 12 + hh) * 64 + dd) << 9);
#pragma unroll
      for (int m = 0; m < 4; ++m) {
        int tq = (brow + wr * 64 + m * 16 + g * 4) & 511;
        ushort4 pk;
        pk.x = f2b(acc[m][n][0] + bv);
        pk.y = f2b(acc[m][n][1] + bv);
        pk.z = f2b(acc[m][n][2] + bv);
        pk.w = f2b(acc[m][n][3] + bv);
        *(ushort4*)(vrow + tq) = pk;
      }
    }
  } else {
#pragma unroll
    for (int n = 0; n < 4; ++n) {
      int c = bcol + wc * 64 + n * 16 + lm;
      float bv = bias[c];
#pragma unroll
      for (int m = 0; m < 4; ++m) {
        int rbase = brow + wr * 64 + m * 16 + g * 4;
#pragma unroll
        for (int j = 0; j < 4; ++j) {
          float v = acc[m][n][j] + bv;
          if (MODE == 0)
            ((u16*)out)[(size_t)(rbase + j) * 1536 + c] = f2b(v);
          else
            ((float*)out)[(size_t)(rbase + j) * N + c] = v;
        }
      }
    }
  }
}

// ---------------- fused flash attention ----------------
// qk: [8192][1536] bf16, cols [0,768)=Q [768,1536)=K. vt: [192][64][512] bf16 (d-major V).
// grid: (b,h,qtile64) = 1536 blocks, 256 threads (4 waves), wave owns 16 q-rows.
// K,V double-buffered via linear gload_lds; mask hoisted to a per-lane bitmask so the
// loop body has NO vmem (no compiler-inserted vmcnt drain of the prefetch).

__global__ __launch_bounds__(256) void attn_fused(const u16* __restrict__ qk,
                                                  const u16* __restrict__ vt,
                                                  const int* __restrict__ mask,
                                                  u16* __restrict__ out) {
  __shared__ __align__(16) u16 Ks[2][64 * 64];     // [key][d], swizzled 16B chunks
  __shared__ __align__(16) u16 Vs[2][64 * 64];     // [d][key], swizzled 16B chunks
  __shared__ __align__(16) u16 Ps[4][16 * 64];     // per-wave P [q16][key64], swizzled

  const int t = threadIdx.x, l = t & 63, w = t >> 6;
  const int lm = l & 15, g = l >> 4;
  // T1 chunked XCD remap: consecutive logical blocks (same b,h -> same K/V panel)
  // stay on one XCD. 1536 % 8 == 0 -> bijective.
  const int bid = (blockIdx.x & 7) * 192 + (blockIdx.x >> 3);
  const int qt = bid & 7;
  const int bh = bid >> 3;
  const int b = bh / 12, h = bh % 12;

  // Q fragments in registers for the whole kernel
  bf16x8 qf[2];
  {
    const u16* qptr = qk + (size_t)(b * 512 + qt * 64 + w * 16 + lm) * 1536 + h * 64;
    qf[0] = *(const bf16x8*)(qptr + g * 8);
    qf[1] = *(const bf16x8*)(qptr + 32 + g * 8);
  }

  // hoist mask to a 32-bit per-lane bitmask: bit (kt*4+n) = mask[kt*64+n*16+lm] != 0
  unsigned mbits = 0;
#pragma unroll
  for (int kt = 0; kt < 8; ++kt)
#pragma unroll
    for (int n = 0; n < 4; ++n)
      mbits |= (mask[b * 512 + kt * 64 + n * 16 + lm] != 0 ? 1u : 0u) << (kt * 4 + n);

  f32x4 o[4] = {};
  float mrun[4], lrun[4];
#pragma unroll
  for (int j = 0; j < 4; ++j) { mrun[j] = -3.0e38f; lrun[j] = 0.f; }

  // staging: thread covers row rk (and rk+32), chunk ck of 8; source chunk XOR-swizzled
  const int rk = t >> 3, ck = t & 7;
  const int cswz = ck ^ (rk & 7);
  const u16* srcK = qk + (size_t)(b * 512 + rk) * 1536 + 768 + h * 64 + cswz * 8;
  const u16* srcV = vt + ((size_t)(bh * 64 + rk)) * 512 + cswz * 8;

  auto stage = [&](int kt, int buf) {
    const size_t offK = (size_t)kt * 64 * 1536;
    gload_lds16(srcK + offK, Ks[buf] + t * 8);
    gload_lds16(srcK + offK + 32 * 1536, Ks[buf] + (t + 256) * 8);
    gload_lds16(srcV + kt * 64, Vs[buf] + t * 8);
    gload_lds16(srcV + kt * 64 + 32 * 512, Vs[buf] + (t + 256) * 8);
  };

  stage(0, 0);
  __syncthreads();
  int cur = 0;

  for (int kt = 0; kt < 8; ++kt) {
    if (kt < 7) stage(kt + 1, cur ^ 1);  // prefetch flies under the whole compute below

    // S = Q K^T  (wave: 16 q x 64 keys)
    f32x4 s[4] = {};
#pragma unroll
    for (int ds = 0; ds < 2; ++ds) {
#pragma unroll
      for (int n = 0; n < 4; ++n) {
        int r = n * 16 + lm;
        bf16x8 kf = lds_read16(Ks[cur] + r * 64 + (((ds * 4 + g) ^ (r & 7)) * 8));
        s[n] = __builtin_amdgcn_mfma_f32_16x16x32_bf16(qf[ds], kf, s[n], 0, 0, 0);
      }
    }
    // scale 1/sqrt(64) and mask from the hoisted bitmask (no vmem here)
#pragma unroll
    for (int n = 0; n < 4; ++n) {
      bool ok = (mbits >> (kt * 4 + n)) & 1u;
#pragma unroll
      for (int j = 0; j < 4; ++j) {
        float sv = s[n][j] * 0.125f;
        s[n][j] = ok ? sv : -3.0e38f;
      }
    }
    // online softmax; lane's rows are q16 = g*4+j, row spread over 16 lanes (lm) x 4 regs (n)
    float alpha[4];
#pragma unroll
    for (int j = 0; j < 4; ++j) {
      float rmax = fmaxf(fmaxf(s[0][j], s[1][j]), fmaxf(s[2][j], s[3][j]));
#pragma unroll
      for (int off = 8; off >= 1; off >>= 1) rmax = fmaxf(rmax, __shfl_xor(rmax, off));
      float mnew = fmaxf(mrun[j], rmax);
      alpha[j] = __expf(mrun[j] - mnew);
      mrun[j] = mnew;
      float rsum = 0.f;
#pragma unroll
      for (int n = 0; n < 4; ++n) {
        float p = __expf(s[n][j] - mnew);
        s[n][j] = p;
        rsum += p;
      }
#pragma unroll
      for (int off = 8; off >= 1; off >>= 1) rsum += __shfl_xor(rsum, off);
      lrun[j] = lrun[j] * alpha[j] + rsum;
    }
#pragma unroll
    for (int n = 0; n < 4; ++n)
#pragma unroll
      for (int j = 0; j < 4; ++j) o[n][j] *= alpha[j];

    // P -> per-wave LDS (bf16, swizzled), then PV MFMA
    u16* pw = Ps[w];
#pragma unroll
    for (int n = 0; n < 4; ++n) {
      int key = n * 16 + lm;
#pragma unroll
      for (int j = 0; j < 4; ++j) {
        int q16 = g * 4 + j;
        pw[q16 * 64 + (((key >> 3) ^ (q16 & 7)) * 8) + (key & 7)] = f2b(s[n][j]);
      }
    }
#pragma unroll
    for (int ks = 0; ks < 2; ++ks) {
      bf16x8 pa = lds_read16(pw + lm * 64 + (((ks * 4 + g) ^ (lm & 7)) * 8));
#pragma unroll
      for (int n = 0; n < 4; ++n) {
        int rd = n * 16 + lm;
        bf16x8 vb = lds_read16(Vs[cur] + rd * 64 + (((ks * 4 + g) ^ (rd & 7)) * 8));
        o[n] = __builtin_amdgcn_mfma_f32_16x16x32_bf16(pa, vb, o[n], 0, 0, 0);
      }
    }
    __syncthreads();  // drains remaining prefetch + all waves done with Ks/Vs[cur]
    cur ^= 1;
  }

  // epilogue: normalize and store bf16 to (b,t) x (h,d)
  float inv[4];
#pragma unroll
  for (int j = 0; j < 4; ++j) inv[j] = 1.0f / lrun[j];
#pragma unroll
  for (int n = 0; n < 4; ++n) {
    int d = n * 16 + lm;
#pragma unroll
    for (int j = 0; j < 4; ++j) {
      int tq = qt * 64 + w * 16 + g * 4 + j;
      out[(size_t)(b * 512 + tq) * 768 + h * 64 + d] = f2b(o[n][j] * inv[j]);
    }
  }
}

// ---------------- launch ----------------

extern "C" void kernel_launch(void* const* d_in, const int* in_sizes, int n_in,
                              void* d_out, int out_size, void* d_ws, size_t ws_size,
                              hipStream_t stream) {
  const float* x = (const float*)d_in[0];
  const int* mask = (const int*)d_in[1];  // harness delivers integer inputs as int32
  const float* Wqkv = (const float*)d_in[2];
  const float* bqkv = (const float*)d_in[3];
  const float* Wproj = (const float*)d_in[4];
  const float* bproj = (const float*)d_in[5];
  float* out = (float*)d_out;

  char* ws = (char*)d_ws;
  u16* xb     = (u16*)(ws);                    // 8192*768*2   = 12,582,912
  u16* wqkvT  = (u16*)(ws + 12582912);         // 2304*768*2   =  3,538,944
  u16* wprojT = (u16*)(ws + 16121856);         // 768*768*2    =  1,179,648
  u16* qkb    = (u16*)(ws + 17301504);         // 8192*1536*2  = 25,165,824
  u16* vtb    = (u16*)(ws + 42467328);         // 192*64*512*2 = 12,582,912
  u16* attnb  = (u16*)(ws + 55050240);         // 8192*768*2   = 12,582,912  (end 67,633,152)

  cvt_x<<<3072, 256, 0, stream>>>(x, xb, 786432);
  transpose_cvt<<<72 * 24, 256, 0, stream>>>(Wqkv, wqkvT, 768, 2304);
  transpose_cvt<<<24 * 24, 256, 0, stream>>>(Wproj, wprojT, 768, 768);
  gemm_bt<0><<<64 * 18, 256, 0, stream>>>(xb, wqkvT, bqkv, qkb, vtb, 8192, 2304, 768);
  attn_fused<<<1536, 256, 0, stream>>>(qkb, vtb, mask, attnb);
  gemm_bt<1><<<64 * 6, 256, 0, stream>>>(attnb, wprojT, bproj, out, nullptr, 8192, 768, 768);
}

// Round 5
// 138.689 us; speedup vs baseline: 1.1141x; 1.0171x over previous
//
#include <hip/hip_runtime.h>

// Fused attention block: qkv = x@Wqkv+b; per-head softmax(QK^T/8)V; y = att@Wproj+b
// B=16 T=512 H=768 NH=12 HS=64. All GEMM/attn compute in bf16 MFMA (16x16x32), fp32 accum.
// R4: qkv GEMM rewritten on the 256x256 8-wave deep-pipelined template (T3+T4+T5):
//     BK=64, 128KB dbuf LDS, 4 phases/K-tile, counted vmcnt(8), setprio around MFMA.
//     Staging writes only to LDS regions proven dead (per-phase region lifetime analysis).

typedef unsigned short u16;
typedef __bf16 bf16x8 __attribute__((ext_vector_type(8)));
typedef float f32x4 __attribute__((ext_vector_type(4)));
typedef unsigned short u16x8 __attribute__((ext_vector_type(8)));

__device__ __forceinline__ u16 f2b(float f) {
  union { float f; unsigned int u; } v; v.f = f;
  unsigned int u = v.u;
  return (u16)((u + 0x7FFFu + ((u >> 16) & 1u)) >> 16);  // RNE
}

__device__ __forceinline__ void gload_lds16(const u16* gsrc, u16* ldst) {
  __builtin_amdgcn_global_load_lds(
      (const __attribute__((address_space(1))) void*)gsrc,
      (__attribute__((address_space(3))) void*)ldst,
      16, 0, 0);
}

__device__ __forceinline__ bf16x8 lds_read16(const u16* p) {
  return __builtin_bit_cast(bf16x8, *(const int4*)p);
}

__device__ __forceinline__ int inc3(int x) { return x == 2 ? 0 : x + 1; }

// ---------------- converts ----------------

__global__ __launch_bounds__(256) void cvt_x(const float* __restrict__ in,
                                             u16* __restrict__ out, int n8) {
  int i = blockIdx.x * 256 + threadIdx.x;
  if (i >= n8) return;
  float4 v0 = ((const float4*)in)[(size_t)i * 2];
  float4 v1 = ((const float4*)in)[(size_t)i * 2 + 1];
  u16x8 r;
  r[0] = f2b(v0.x); r[1] = f2b(v0.y); r[2] = f2b(v0.z); r[3] = f2b(v0.w);
  r[4] = f2b(v1.x); r[5] = f2b(v1.y); r[6] = f2b(v1.z); r[7] = f2b(v1.w);
  *(u16x8*)(out + (size_t)i * 8) = r;
}

// in[R][C] fp32 -> out[C][R] bf16
__global__ __launch_bounds__(256) void transpose_cvt(const float* __restrict__ in,
                                                     u16* __restrict__ out, int R, int C) {
  __shared__ float tile[32][33];
  int nbx = C >> 5;
  int bx = blockIdx.x % nbx, by = blockIdx.x / nbx;
  int tx = threadIdx.x & 31, ty = threadIdx.x >> 5;  // 32 x 8
#pragma unroll
  for (int jj = 0; jj < 32; jj += 8)
    tile[ty + jj][tx] = in[(size_t)(by * 32 + ty + jj) * C + bx * 32 + tx];
  __syncthreads();
#pragma unroll
  for (int jj = 0; jj < 32; jj += 8)
    out[(size_t)(bx * 32 + ty + jj) * R + by * 32 + tx] = f2b(tile[tx][ty + jj]);
}

// ---------------- qkv GEMM: 256x256 tile, 8 waves, BK=64, deep pipeline ----------------
// A[8192][768] bf16, Bt[2304][768] bf16. Output: cols<1536 -> qk[8192][1536] bf16;
// cols>=1536 (V) -> vt[b,h][d][t] bf16 transposed.
// Waves 2(M) x 4(N); wave tile 128x64 = acc[8][4]. 4 phases/K-tile, quadrant order
// (mh,nh) = (0,0),(0,1),(1,1),(1,0). Stage schedule targets dead regions only:
//   a0(A rows 0-63), a2(128-191) die after ph0 -> staged ph1
//   b0..b3 (all B rows) die after ph1        -> staged ph2 (b0,b1), ph3 (b2,b3)
//   a1(64-127), a3(192-255) die after ph2    -> staged ph3
// vmcnt(8) once per K-tile (before ph3 barrier): waits tile kt+1's 8 loads, keeps
// this tile's 8 (for kt+2) in flight.

__global__ __launch_bounds__(512, 2) void gemm_qkv(const u16* __restrict__ A,
                                                   const u16* __restrict__ Bt,
                                                   const float* __restrict__ bias,
                                                   u16* __restrict__ qk,
                                                   u16* __restrict__ vt) {
  constexpr int K = 768, KT = 12, NBX = 9;
  __shared__ __align__(16) u16 As[2][256 * 64];
  __shared__ __align__(16) u16 Bs[2][256 * 64];
  const int t = threadIdx.x, l = t & 63, w = t >> 6;
  const int wr = w >> 2, wc = w & 3;  // 2 x 4 wave grid
  const int lm = l & 15, g = l >> 4;
  const int cpx = gridDim.x >> 3;  // 288/8 = 36; bijective XCD chunk remap
  const int bid = (blockIdx.x & 7) * cpx + (blockIdx.x >> 3);
  const int brow = (bid / NBX) << 8;
  const int bcol = (bid % NBX) << 8;

  f32x4 acc[8][4] = {};

  // staging: thread covers row rt = t>>3 of each 64-row round, chunk ck = t&7 of 8.
  // XOR swizzle on SOURCE chunk; same XOR on read side (both-sides, rule #21).
  const int rt = t >> 3, ck = t & 7;
  const int cswz = (ck ^ (rt & 7)) * 8;  // (p*64+rt)&7 == rt&7 for all rounds p
  const u16* gA = A + (size_t)(brow + rt) * K + cswz;
  const u16* gB = Bt + (size_t)(bcol + rt) * K + cswz;

  auto stageA = [&](int kt, int buf, int p) {
    gload_lds16(gA + (size_t)p * 64 * K + kt * 64, As[buf] + p * 4096 + t * 8);
  };
  auto stageB = [&](int kt, int buf, int p) {
    gload_lds16(gB + (size_t)p * 64 * K + kt * 64, Bs[buf] + p * 4096 + t * 8);
  };
  // read A-half mh: 4 row-frags x 2 k-slices (8 x ds_read_b128)
  auto readA = [&](int cur, int mh, bf16x8 a[4][2]) {
#pragma unroll
    for (int m = 0; m < 4; ++m) {
      int r = wr * 128 + (mh * 4 + m) * 16 + lm;
#pragma unroll
      for (int ks = 0; ks < 2; ++ks)
        a[m][ks] = lds_read16(As[cur] + r * 64 + (((ks * 4 + g) ^ (lm & 7)) * 8));
    }
  };
  // read B-half nh: 2 col-frags x 2 k-slices (4 x ds_read_b128)
  auto readB = [&](int cur, int nh, bf16x8 b[2][2]) {
#pragma unroll
    for (int n = 0; n < 2; ++n) {
      int r = wc * 64 + (nh * 2 + n) * 16 + lm;
#pragma unroll
      for (int ks = 0; ks < 2; ++ks)
        b[n][ks] = lds_read16(Bs[cur] + r * 64 + (((ks * 4 + g) ^ (lm & 7)) * 8));
    }
  };
  // 16 MFMA quadrant under setprio (T5)
  auto mmac = [&](int mh, int nh, bf16x8 a[4][2], bf16x8 b[2][2]) {
    __builtin_amdgcn_s_setprio(1);
#pragma unroll
    for (int m = 0; m < 4; ++m)
#pragma unroll
      for (int n = 0; n < 2; ++n)
#pragma unroll
        for (int ks = 0; ks < 2; ++ks)
          acc[mh * 4 + m][nh * 2 + n] = __builtin_amdgcn_mfma_f32_16x16x32_bf16(
              a[m][ks], b[n][ks], acc[mh * 4 + m][nh * 2 + n], 0, 0, 0);
    __builtin_amdgcn_s_setprio(0);
  };

  // prologue: stage kt=0 (buf0, 8 loads) then kt=1 (buf1, 8 loads); wait kt0 only.
#pragma unroll
  for (int p = 0; p < 4; ++p) stageA(0, 0, p);
#pragma unroll
  for (int p = 0; p < 4; ++p) stageB(0, 0, p);
#pragma unroll
  for (int p = 0; p < 4; ++p) stageA(1, 1, p);
#pragma unroll
  for (int p = 0; p < 4; ++p) stageB(1, 1, p);
  asm volatile("s_waitcnt vmcnt(8)" ::: "memory");
  __builtin_amdgcn_s_barrier();
  __builtin_amdgcn_sched_barrier(0);

  for (int kt = 0; kt < KT; ++kt) {
    const int cur = kt & 1;
    const bool S = (kt + 2 < KT);
    bf16x8 a[4][2], b0[2][2], b1[2][2];
    // ---- phase 0: read A0,B0; mfma (0,0)
    readA(cur, 0, a);
    readB(cur, 0, b0);
    __builtin_amdgcn_s_barrier();
    __builtin_amdgcn_sched_barrier(0);
    mmac(0, 0, a, b0);
    __builtin_amdgcn_s_barrier();
    // ---- phase 1: read B1; stage a0,a2 (dead after ph0); mfma (0,1)
    readB(cur, 1, b1);
    if (S) { stageA(kt + 2, cur, 0); stageA(kt + 2, cur, 2); }
    __builtin_amdgcn_s_barrier();
    __builtin_amdgcn_sched_barrier(0);
    mmac(0, 1, a, b1);
    __builtin_amdgcn_s_barrier();
    // ---- phase 2: read A1; stage b0,b1 (dead after ph1); mfma (1,1)
    readA(cur, 1, a);
    if (S) { stageB(kt + 2, cur, 0); stageB(kt + 2, cur, 1); }
    __builtin_amdgcn_s_barrier();
    __builtin_amdgcn_sched_barrier(0);
    mmac(1, 1, a, b1);
    __builtin_amdgcn_s_barrier();
    // ---- phase 3: stage b2,b3 (dead ph1) + a1,a3 (dead ph2); counted vmcnt; mfma (1,0)
    if (S) {
      stageB(kt + 2, cur, 2); stageB(kt + 2, cur, 3);
      stageA(kt + 2, cur, 1); stageA(kt + 2, cur, 3);
    }
    __builtin_amdgcn_sched_barrier(0);
    if (S) {
      asm volatile("s_waitcnt vmcnt(8)" ::: "memory");  // kt+1's loads done; kt+2's fly
    } else {
      asm volatile("s_waitcnt vmcnt(0)" ::: "memory");  // epilogue drain
    }
    __builtin_amdgcn_s_barrier();
    __builtin_amdgcn_sched_barrier(0);
    mmac(1, 0, a, b0);
    __builtin_amdgcn_s_barrier();
  }

  // epilogue
  if (bcol >= 1536) {
    const int b = brow >> 9;
#pragma unroll
    for (int n = 0; n < 4; ++n) {
      int cv = bcol - 1536 + wc * 64 + n * 16 + lm;
      int hh = cv >> 6, dd = cv & 63;
      float bv = bias[1536 + cv];
      u16* vrow = vt + (((size_t)(b * 12 + hh) * 64 + dd) << 9);
#pragma unroll
      for (int m = 0; m < 8; ++m) {
        int tq = (brow + wr * 128 + m * 16 + g * 4) & 511;
        ushort4 pk;
        pk.x = f2b(acc[m][n][0] + bv);
        pk.y = f2b(acc[m][n][1] + bv);
        pk.z = f2b(acc[m][n][2] + bv);
        pk.w = f2b(acc[m][n][3] + bv);
        *(ushort4*)(vrow + tq) = pk;
      }
    }
  } else {
#pragma unroll
    for (int n = 0; n < 4; ++n) {
      int c = bcol + wc * 64 + n * 16 + lm;
      float bv = bias[c];
#pragma unroll
      for (int m = 0; m < 8; ++m) {
        int rbase = brow + wr * 128 + m * 16 + g * 4;
#pragma unroll
        for (int j = 0; j < 4; ++j)
          qk[(size_t)(rbase + j) * 1536 + c] = f2b(acc[m][n][j] + bv);
      }
    }
  }
}

// ---------------- proj GEMM: 128x128 tile, depth-3 pipeline (round-4 verified) ----------
__global__ __launch_bounds__(256) void gemm_proj(const u16* __restrict__ A,
                                                 const u16* __restrict__ Bt,
                                                 const float* __restrict__ bias,
                                                 float* __restrict__ out,
                                                 int M, int N, int K) {
  __shared__ __align__(16) u16 As[3][128 * 32];
  __shared__ __align__(16) u16 Bs[3][128 * 32];
  const int t = threadIdx.x;
  const int l = t & 63;
  const int w = t >> 6;
  const int wr = w >> 1, wc = w & 1;
  const int lm = l & 15, g = l >> 4;
  const int nbx = N >> 7;
  const int cpx = gridDim.x >> 3;
  const int bid = (blockIdx.x & 7) * cpx + (blockIdx.x >> 3);
  const int brow = (bid / nbx) << 7;
  const int bcol = (bid % nbx) << 7;

  f32x4 acc[4][4] = {};

  const int r0 = t >> 2;
  const int c0 = t & 3;
  const int swz0 = (c0 ^ ((r0 >> 1) & 3)) * 8;
  const u16* gA0 = A + (size_t)(brow + r0) * K + swz0;
  const u16* gA1 = A + (size_t)(brow + r0 + 64) * K + swz0;
  const u16* gB0 = Bt + (size_t)(bcol + r0) * K + swz0;
  const u16* gB1 = Bt + (size_t)(bcol + r0 + 64) * K + swz0;

  const int KT = K >> 5;
  auto stage = [&](int kt, int buf) {
    const int k0 = kt << 5;
    gload_lds16(gA0 + k0, As[buf] + t * 8);
    gload_lds16(gA1 + k0, As[buf] + (t + 256) * 8);
    gload_lds16(gB0 + k0, Bs[buf] + t * 8);
    gload_lds16(gB1 + k0, Bs[buf] + (t + 256) * 8);
  };

  stage(0, 0);
  stage(1, 1);
  asm volatile("s_waitcnt vmcnt(4)" ::: "memory");
  __builtin_amdgcn_s_barrier();
  __builtin_amdgcn_sched_barrier(0);

  int cur = 0, pre = 2;
  for (int kt = 0; kt < KT; ++kt) {
    if (kt + 2 < KT) stage(kt + 2, pre);
    bf16x8 af[4], bf_[4];
#pragma unroll
    for (int m = 0; m < 4; ++m) {
      int r = wr * 64 + m * 16 + lm;
      af[m] = lds_read16(As[cur] + r * 32 + ((g ^ ((r >> 1) & 3)) * 8));
    }
#pragma unroll
    for (int n = 0; n < 4; ++n) {
      int r = wc * 64 + n * 16 + lm;
      bf_[n] = lds_read16(Bs[cur] + r * 32 + ((g ^ ((r >> 1) & 3)) * 8));
    }
#pragma unroll
    for (int m = 0; m < 4; ++m)
#pragma unroll
      for (int n = 0; n < 4; ++n)
        acc[m][n] = __builtin_amdgcn_mfma_f32_16x16x32_bf16(af[m], bf_[n], acc[m][n], 0, 0, 0);
    __builtin_amdgcn_sched_barrier(0);
    if (kt + 2 < KT) {
      asm volatile("s_waitcnt vmcnt(4)" ::: "memory");
    } else {
      asm volatile("s_waitcnt vmcnt(0)" ::: "memory");
    }
    __builtin_amdgcn_s_barrier();
    __builtin_amdgcn_sched_barrier(0);
    cur = inc3(cur);
    pre = inc3(pre);
  }

#pragma unroll
  for (int n = 0; n < 4; ++n) {
    int c = bcol + wc * 64 + n * 16 + lm;
    float bv = bias[c];
#pragma unroll
    for (int m = 0; m < 4; ++m) {
      int rbase = brow + wr * 64 + m * 16 + g * 4;
#pragma unroll
      for (int j = 0; j < 4; ++j)
        out[(size_t)(rbase + j) * N + c] = acc[m][n][j] + bv;
    }
  }
}

// ---------------- fused flash attention (round-4 verified) ----------------
__global__ __launch_bounds__(256) void attn_fused(const u16* __restrict__ qk,
                                                  const u16* __restrict__ vt,
                                                  const int* __restrict__ mask,
                                                  u16* __restrict__ out) {
  __shared__ __align__(16) u16 Ks[2][64 * 64];
  __shared__ __align__(16) u16 Vs[2][64 * 64];
  __shared__ __align__(16) u16 Ps[4][16 * 64];

  const int t = threadIdx.x, l = t & 63, w = t >> 6;
  const int lm = l & 15, g = l >> 4;
  const int bid = (blockIdx.x & 7) * 192 + (blockIdx.x >> 3);
  const int qt = bid & 7;
  const int bh = bid >> 3;
  const int b = bh / 12, h = bh % 12;

  bf16x8 qf[2];
  {
    const u16* qptr = qk + (size_t)(b * 512 + qt * 64 + w * 16 + lm) * 1536 + h * 64;
    qf[0] = *(const bf16x8*)(qptr + g * 8);
    qf[1] = *(const bf16x8*)(qptr + 32 + g * 8);
  }

  unsigned mbits = 0;
#pragma unroll
  for (int kt = 0; kt < 8; ++kt)
#pragma unroll
    for (int n = 0; n < 4; ++n)
      mbits |= (mask[b * 512 + kt * 64 + n * 16 + lm] != 0 ? 1u : 0u) << (kt * 4 + n);

  f32x4 o[4] = {};
  float mrun[4], lrun[4];
#pragma unroll
  for (int j = 0; j < 4; ++j) { mrun[j] = -3.0e38f; lrun[j] = 0.f; }

  const int rk = t >> 3, ck = t & 7;
  const int cswz = ck ^ (rk & 7);
  const u16* srcK = qk + (size_t)(b * 512 + rk) * 1536 + 768 + h * 64 + cswz * 8;
  const u16* srcV = vt + ((size_t)(bh * 64 + rk)) * 512 + cswz * 8;

  auto stage = [&](int kt, int buf) {
    const size_t offK = (size_t)kt * 64 * 1536;
    gload_lds16(srcK + offK, Ks[buf] + t * 8);
    gload_lds16(srcK + offK + 32 * 1536, Ks[buf] + (t + 256) * 8);
    gload_lds16(srcV + kt * 64, Vs[buf] + t * 8);
    gload_lds16(srcV + kt * 64 + 32 * 512, Vs[buf] + (t + 256) * 8);
  };

  stage(0, 0);
  __syncthreads();
  int cur = 0;

  for (int kt = 0; kt < 8; ++kt) {
    if (kt < 7) stage(kt + 1, cur ^ 1);

    f32x4 s[4] = {};
#pragma unroll
    for (int ds = 0; ds < 2; ++ds) {
#pragma unroll
      for (int n = 0; n < 4; ++n) {
        int r = n * 16 + lm;
        bf16x8 kf = lds_read16(Ks[cur] + r * 64 + (((ds * 4 + g) ^ (r & 7)) * 8));
        s[n] = __builtin_amdgcn_mfma_f32_16x16x32_bf16(qf[ds], kf, s[n], 0, 0, 0);
      }
    }
#pragma unroll
    for (int n = 0; n < 4; ++n) {
      bool ok = (mbits >> (kt * 4 + n)) & 1u;
#pragma unroll
      for (int j = 0; j < 4; ++j) {
        float sv = s[n][j] * 0.125f;
        s[n][j] = ok ? sv : -3.0e38f;
      }
    }
    float alpha[4];
#pragma unroll
    for (int j = 0; j < 4; ++j) {
      float rmax = fmaxf(fmaxf(s[0][j], s[1][j]), fmaxf(s[2][j], s[3][j]));
#pragma unroll
      for (int off = 8; off >= 1; off >>= 1) rmax = fmaxf(rmax, __shfl_xor(rmax, off));
      float mnew = fmaxf(mrun[j], rmax);
      alpha[j] = __expf(mrun[j] - mnew);
      mrun[j] = mnew;
      float rsum = 0.f;
#pragma unroll
      for (int n = 0; n < 4; ++n) {
        float p = __expf(s[n][j] - mnew);
        s[n][j] = p;
        rsum += p;
      }
#pragma unroll
      for (int off = 8; off >= 1; off >>= 1) rsum += __shfl_xor(rsum, off);
      lrun[j] = lrun[j] * alpha[j] + rsum;
    }
#pragma unroll
    for (int n = 0; n < 4; ++n)
#pragma unroll
      for (int j = 0; j < 4; ++j) o[n][j] *= alpha[j];

    u16* pw = Ps[w];
#pragma unroll
    for (int n = 0; n < 4; ++n) {
      int key = n * 16 + lm;
#pragma unroll
      for (int j = 0; j < 4; ++j) {
        int q16 = g * 4 + j;
        pw[q16 * 64 + (((key >> 3) ^ (q16 & 7)) * 8) + (key & 7)] = f2b(s[n][j]);
      }
    }
#pragma unroll
    for (int ks = 0; ks < 2; ++ks) {
      bf16x8 pa = lds_read16(pw + lm * 64 + (((ks * 4 + g) ^ (lm & 7)) * 8));
#pragma unroll
      for (int n = 0; n < 4; ++n) {
        int rd = n * 16 + lm;
        bf16x8 vb = lds_read16(Vs[cur] + rd * 64 + (((ks * 4 + g) ^ (rd & 7)) * 8));
        o[n] = __builtin_amdgcn_mfma_f32_16x16x32_bf16(pa, vb, o[n], 0, 0, 0);
      }
    }
    __syncthreads();
    cur ^= 1;
  }

  float inv[4];
#pragma unroll
  for (int j = 0; j < 4; ++j) inv[j] = 1.0f / lrun[j];
#pragma unroll
  for (int n = 0; n < 4; ++n) {
    int d = n * 16 + lm;
#pragma unroll
    for (int j = 0; j < 4; ++j) {
      int tq = qt * 64 + w * 16 + g * 4 + j;
      out[(size_t)(b * 512 + tq) * 768 + h * 64 + d] = f2b(o[n][j] * inv[j]);
    }
  }
}

// ---------------- launch ----------------

extern "C" void kernel_launch(void* const* d_in, const int* in_sizes, int n_in,
                              void* d_out, int out_size, void* d_ws, size_t ws_size,
                              hipStream_t stream) {
  const float* x = (const float*)d_in[0];
  const int* mask = (const int*)d_in[1];
  const float* Wqkv = (const float*)d_in[2];
  const float* bqkv = (const float*)d_in[3];
  const float* Wproj = (const float*)d_in[4];
  const float* bproj = (const float*)d_in[5];
  float* out = (float*)d_out;

  char* ws = (char*)d_ws;
  u16* xb     = (u16*)(ws);                    // 8192*768*2   = 12,582,912
  u16* wqkvT  = (u16*)(ws + 12582912);         // 2304*768*2   =  3,538,944
  u16* wprojT = (u16*)(ws + 16121856);         // 768*768*2    =  1,179,648
  u16* qkb    = (u16*)(ws + 17301504);         // 8192*1536*2  = 25,165,824
  u16* vtb    = (u16*)(ws + 42467328);         // 192*64*512*2 = 12,582,912
  u16* attnb  = (u16*)(ws + 55050240);         // 8192*768*2   = 12,582,912  (end 67,633,152)

  cvt_x<<<3072, 256, 0, stream>>>(x, xb, 786432);
  transpose_cvt<<<72 * 24, 256, 0, stream>>>(Wqkv, wqkvT, 768, 2304);
  transpose_cvt<<<24 * 24, 256, 0, stream>>>(Wproj, wprojT, 768, 768);
  gemm_qkv<<<288, 512, 0, stream>>>(xb, wqkvT, bqkv, qkb, vtb);
  attn_fused<<<1536, 256, 0, stream>>>(qkb, vtb, mask, attnb);
  gemm_proj<<<384, 256, 0, stream>>>(attnb, wprojT, bproj, out, 8192, 768, 768);
}